// Round 1
// baseline (441.889 us; speedup 1.0000x reference)
//
#include <hip/hip_runtime.h>
#include <math.h>

#define Nn 10000
#define Ee 320000
#define EE 330000      // E + N self loops
#define INF_ 256
#define HID 128
#define OUTC 128
#define NH 4
#define F1 512         // NH*HID
#define F2 512         // NH*OUTC
#define SLOPE 0.2f

static __device__ __forceinline__ float lrelu(float x) { return fmaxf(x, SLOPE * x); }

// ---------------- CSR build ----------------
__global__ void init_counts(int* counts) {
    int i = blockIdx.x * 256 + threadIdx.x;
    if (i < Nn) counts[i] = 1;  // self loop
}

__global__ void count_edges(const int* __restrict__ ei, int* counts) {
    int e = blockIdx.x * 256 + threadIdx.x;
    if (e < Ee) atomicAdd(&counts[ei[Ee + e]], 1);
}

__global__ __launch_bounds__(1024) void scan_kernel(const int* __restrict__ counts,
                                                    int* __restrict__ offsets) {
    __shared__ int sd[1024];
    int tid = threadIdx.x;
    int carry = 0;
    for (int base = 0; base < Nn; base += 1024) {
        int i = base + tid;
        int v = (i < Nn) ? counts[i] : 0;
        sd[tid] = v;
        __syncthreads();
        int x = v;
        for (int off = 1; off < 1024; off <<= 1) {
            int t = (tid >= off) ? sd[tid - off] : 0;
            __syncthreads();
            x += t;
            sd[tid] = x;
            __syncthreads();
        }
        if (i < Nn) offsets[i] = carry + x - v;  // exclusive
        int total = sd[1023];
        __syncthreads();
        carry += total;
    }
    if (tid == 0) offsets[Nn] = carry;
}

__global__ void copy_cursor(const int* __restrict__ offsets, int* cursor) {
    int i = blockIdx.x * 256 + threadIdx.x;
    if (i < Nn) cursor[i] = offsets[i];
}

__global__ void scatter_edges(const int* __restrict__ ei, int* cursor, int* __restrict__ csr) {
    int t = blockIdx.x * 256 + threadIdx.x;
    if (t >= EE) return;
    int src, dst;
    if (t < Ee) { src = ei[t]; dst = ei[Ee + t]; }
    else        { src = t - Ee; dst = t - Ee; }
    int pos = atomicAdd(&cursor[dst], 1);
    csr[pos] = src;
}

// ---------------- fp32 tiled GEMM (64x64x16, 4x4 per thread) ----------------
__global__ __launch_bounds__(256) void gemm64(const float* __restrict__ A,
                                              const float* __restrict__ B,
                                              float* __restrict__ C,
                                              int M, int N, int K) {
    __shared__ float As[16][64];
    __shared__ float Bs[16][64];
    const int tid = threadIdx.x;
    const int bm = blockIdx.x * 64, bn = blockIdx.y * 64;
    const int tx = tid & 15, ty = tid >> 4;
    const int arow = tid >> 2, acol = (tid & 3) << 2;
    const int brow = tid >> 4, bcol = (tid & 15) << 2;
    float acc[4][4] = {};
    for (int k0 = 0; k0 < K; k0 += 16) {
        float4 av;
        int gm = bm + arow;
        if (gm < M) av = *(const float4*)(A + (size_t)gm * K + k0 + acol);
        else av = make_float4(0.f, 0.f, 0.f, 0.f);
        As[acol + 0][arow] = av.x;
        As[acol + 1][arow] = av.y;
        As[acol + 2][arow] = av.z;
        As[acol + 3][arow] = av.w;
        *(float4*)&Bs[brow][bcol] = *(const float4*)(B + (size_t)(k0 + brow) * N + bn + bcol);
        __syncthreads();
#pragma unroll
        for (int k = 0; k < 16; k++) {
            float4 a = *(const float4*)&As[k][ty << 2];
            float4 b = *(const float4*)&Bs[k][tx << 2];
            float ar[4] = {a.x, a.y, a.z, a.w};
            float br[4] = {b.x, b.y, b.z, b.w};
#pragma unroll
            for (int i = 0; i < 4; i++)
#pragma unroll
                for (int j = 0; j < 4; j++) acc[i][j] += ar[i] * br[j];
        }
        __syncthreads();
    }
#pragma unroll
    for (int i = 0; i < 4; i++) {
        int gm = bm + (ty << 2) + i;
        if (gm < M) {
            float4 o = make_float4(acc[i][0], acc[i][1], acc[i][2], acc[i][3]);
            *(float4*)(C + (size_t)gm * N + bn + (tx << 2)) = o;
        }
    }
}

// ---------------- alpha_s / alpha_d per (node, head) ----------------
// block = 256 (4 waves), one node per block, one head per wave; C=128 channels
__global__ __launch_bounds__(256) void alphas_kernel(const float* __restrict__ h,
                                                     const float* __restrict__ a_src,
                                                     const float* __restrict__ a_dst,
                                                     float* __restrict__ as_out,
                                                     float* __restrict__ ad_out) {
    int n = blockIdx.x;
    int head = threadIdx.x >> 6;
    int lane = threadIdx.x & 63;
    const float* hp = h + (size_t)n * F1 + head * 128 + lane * 2;
    const float* sp = a_src + head * 128 + lane * 2;
    const float* dp = a_dst + head * 128 + lane * 2;
    float2 hv = *(const float2*)hp;
    float2 sv = *(const float2*)sp;
    float2 dv = *(const float2*)dp;
    float s = hv.x * sv.x + hv.y * sv.y;
    float d = hv.x * dv.x + hv.y * dv.y;
    for (int off = 32; off > 0; off >>= 1) {
        s += __shfl_xor(s, off);
        d += __shfl_xor(d, off);
    }
    if (lane == 0) {
        as_out[n * NH + head] = s;
        ad_out[n * NH + head] = d;
    }
}

// ---------------- softmax pass A: per-node max + exp + denom ----------------
// block 256 = 4 waves, wave = one node
__global__ __launch_bounds__(256) void passA(const int* __restrict__ offsets,
                                             const int* __restrict__ csr,
                                             const float* __restrict__ as,
                                             const float* __restrict__ ad,
                                             float* __restrict__ wedge,
                                             float* __restrict__ invd) {
    int n = blockIdx.x * 4 + (threadIdx.x >> 6);
    int lane = threadIdx.x & 63;
    int start = offsets[n], end = offsets[n + 1];
    float4 adv = *(const float4*)&ad[n * NH];
    float m0 = -1e30f, m1 = -1e30f, m2 = -1e30f, m3 = -1e30f;
    for (int idx = start + lane; idx < end; idx += 64) {
        int src = csr[idx];
        float4 asv = *(const float4*)&as[src * NH];
        m0 = fmaxf(m0, lrelu(asv.x + adv.x));
        m1 = fmaxf(m1, lrelu(asv.y + adv.y));
        m2 = fmaxf(m2, lrelu(asv.z + adv.z));
        m3 = fmaxf(m3, lrelu(asv.w + adv.w));
    }
    for (int off = 32; off > 0; off >>= 1) {
        m0 = fmaxf(m0, __shfl_xor(m0, off));
        m1 = fmaxf(m1, __shfl_xor(m1, off));
        m2 = fmaxf(m2, __shfl_xor(m2, off));
        m3 = fmaxf(m3, __shfl_xor(m3, off));
    }
    float s0 = 0.f, s1 = 0.f, s2 = 0.f, s3 = 0.f;
    for (int idx = start + lane; idx < end; idx += 64) {
        int src = csr[idx];
        float4 asv = *(const float4*)&as[src * NH];
        float e0 = __expf(lrelu(asv.x + adv.x) - m0);
        float e1 = __expf(lrelu(asv.y + adv.y) - m1);
        float e2 = __expf(lrelu(asv.z + adv.z) - m2);
        float e3 = __expf(lrelu(asv.w + adv.w) - m3);
        *(float4*)&wedge[(size_t)idx * NH] = make_float4(e0, e1, e2, e3);
        s0 += e0; s1 += e1; s2 += e2; s3 += e3;
    }
    for (int off = 32; off > 0; off >>= 1) {
        s0 += __shfl_xor(s0, off);
        s1 += __shfl_xor(s1, off);
        s2 += __shfl_xor(s2, off);
        s3 += __shfl_xor(s3, off);
    }
    if (lane == 0) {
        *(float4*)&invd[n * NH] = make_float4(1.f / (s0 + 1e-16f), 1.f / (s1 + 1e-16f),
                                              1.f / (s2 + 1e-16f), 1.f / (s3 + 1e-16f));
    }
}

// ---------------- pass B layer 1: weighted aggregate + bias + relu ----------------
// block 256, one node per block, each thread owns 2 channels of 512
__global__ __launch_bounds__(256) void passB1(const int* __restrict__ offsets,
                                              const int* __restrict__ csr,
                                              const float* __restrict__ wedge,
                                              const float* __restrict__ invd,
                                              const float* __restrict__ h1,
                                              const float* __restrict__ b1,
                                              float* __restrict__ agg) {
    int n = blockIdx.x;
    int c = threadIdx.x * 2;
    int head = threadIdx.x >> 6;
    int start = offsets[n], end = offsets[n + 1];
    float inv = invd[n * NH + head];
    float ax = 0.f, ay = 0.f;
    int idx = start;
    for (; idx + 1 < end; idx += 2) {
        int s0 = csr[idx], s1 = csr[idx + 1];
        float w0 = wedge[(size_t)idx * NH + head];
        float w1 = wedge[(size_t)(idx + 1) * NH + head];
        float2 v0 = *(const float2*)&h1[(size_t)s0 * F1 + c];
        float2 v1 = *(const float2*)&h1[(size_t)s1 * F1 + c];
        ax += v0.x * w0 + v1.x * w1;
        ay += v0.y * w0 + v1.y * w1;
    }
    if (idx < end) {
        int s0 = csr[idx];
        float w0 = wedge[(size_t)idx * NH + head];
        float2 v0 = *(const float2*)&h1[(size_t)s0 * F1 + c];
        ax += v0.x * w0;
        ay += v0.y * w0;
    }
    float ox = fmaxf(ax * inv + b1[c], 0.f);
    float oy = fmaxf(ay * inv + b1[c + 1], 0.f);
    *(float2*)&agg[(size_t)n * F1 + c] = make_float2(ox, oy);
}

// ---------------- pass B layer 2: aggregate + head-mean + bias -> d_out ----------------
// block 128, one node per block, thread owns channel c, 4 head accumulators
__global__ __launch_bounds__(128) void passB2(const int* __restrict__ offsets,
                                              const int* __restrict__ csr,
                                              const float* __restrict__ wedge,
                                              const float* __restrict__ invd,
                                              const float* __restrict__ h2,
                                              const float* __restrict__ b2,
                                              float* __restrict__ out) {
    int n = blockIdx.x;
    int c = threadIdx.x;
    int start = offsets[n], end = offsets[n + 1];
    float4 inv = *(const float4*)&invd[n * NH];
    float a0 = 0.f, a1 = 0.f, a2 = 0.f, a3 = 0.f;
    int idx = start;
    for (; idx + 1 < end; idx += 2) {
        int s0 = csr[idx], s1 = csr[idx + 1];
        float4 w0 = *(const float4*)&wedge[(size_t)idx * NH];
        float4 w1 = *(const float4*)&wedge[(size_t)(idx + 1) * NH];
        const float* r0 = h2 + (size_t)s0 * F2 + c;
        const float* r1 = h2 + (size_t)s1 * F2 + c;
        a0 += r0[0] * w0.x + r1[0] * w1.x;
        a1 += r0[128] * w0.y + r1[128] * w1.y;
        a2 += r0[256] * w0.z + r1[256] * w1.z;
        a3 += r0[384] * w0.w + r1[384] * w1.w;
    }
    if (idx < end) {
        int s0 = csr[idx];
        float4 w0 = *(const float4*)&wedge[(size_t)idx * NH];
        const float* r0 = h2 + (size_t)s0 * F2 + c;
        a0 += r0[0] * w0.x;
        a1 += r0[128] * w0.y;
        a2 += r0[256] * w0.z;
        a3 += r0[384] * w0.w;
    }
    float o = 0.25f * (a0 * inv.x + a1 * inv.y + a2 * inv.z + a3 * inv.w) + b2[c];
    out[(size_t)n * OUTC + c] = o;
}

extern "C" void kernel_launch(void* const* d_in, const int* in_sizes, int n_in,
                              void* d_out, int out_size, void* d_ws, size_t ws_size,
                              hipStream_t stream) {
    const float* x      = (const float*)d_in[0];
    const int*   ei     = (const int*)d_in[1];
    const float* W1     = (const float*)d_in[2];
    const float* a_src1 = (const float*)d_in[3];
    const float* a_dst1 = (const float*)d_in[4];
    const float* b1     = (const float*)d_in[5];
    const float* W2     = (const float*)d_in[6];
    const float* a_src2 = (const float*)d_in[7];
    const float* a_dst2 = (const float*)d_in[8];
    const float* b2     = (const float*)d_in[9];
    float* out = (float*)d_out;

    const size_t NF = (size_t)Nn * F1;  // 5,120,000
    float* f = (float*)d_ws;
    float* h1    = f;
    float* h2    = h1 + NF;
    float* agg1  = h2 + NF;
    float* as1   = agg1 + NF;
    float* ad1   = as1 + Nn * NH;
    float* as2   = ad1 + Nn * NH;
    float* ad2   = as2 + Nn * NH;
    float* invd1 = ad2 + Nn * NH;
    float* invd2 = invd1 + Nn * NH;
    float* wedge = invd2 + Nn * NH;     // EE*NH floats
    int* counts  = (int*)(wedge + (size_t)EE * NH);
    int* offsets = counts + Nn;
    int* cursor  = offsets + Nn + 1;
    int* csr     = cursor + Nn;

    // CSR build
    init_counts<<<(Nn + 255) / 256, 256, 0, stream>>>(counts);
    count_edges<<<(Ee + 255) / 256, 256, 0, stream>>>(ei, counts);
    scan_kernel<<<1, 1024, 0, stream>>>(counts, offsets);
    copy_cursor<<<(Nn + 255) / 256, 256, 0, stream>>>(offsets, cursor);
    scatter_edges<<<(EE + 255) / 256, 256, 0, stream>>>(ei, cursor, csr);

    // Layer 1
    gemm64<<<dim3((Nn + 63) / 64, F1 / 64), 256, 0, stream>>>(x, W1, h1, Nn, F1, INF_);
    alphas_kernel<<<Nn, 256, 0, stream>>>(h1, a_src1, a_dst1, as1, ad1);
    passA<<<Nn / 4, 256, 0, stream>>>(offsets, csr, as1, ad1, wedge, invd1);
    passB1<<<Nn, 256, 0, stream>>>(offsets, csr, wedge, invd1, h1, b1, agg1);

    // Layer 2
    gemm64<<<dim3((Nn + 63) / 64, F2 / 64), 256, 0, stream>>>(agg1, W2, h2, Nn, F2, F1);
    alphas_kernel<<<Nn, 256, 0, stream>>>(h2, a_src2, a_dst2, as2, ad2);
    passA<<<Nn / 4, 256, 0, stream>>>(offsets, csr, as2, ad2, wedge, invd2);
    passB2<<<Nn, 128, 0, stream>>>(offsets, csr, wedge, invd2, h2, b2, out);
}

// Round 2
// 431.774 us; speedup vs baseline: 1.0234x; 1.0234x over previous
//
#include <hip/hip_runtime.h>
#include <math.h>

#define Nn 10000
#define Ee 320000
#define EE 330000      // E + N self loops
#define INF_ 256
#define HID 128
#define OUTC 128
#define NH 4
#define F1 512         // NH*HID
#define F2 512         // NH*OUTC
#define SLOPE 0.2f
#define NB 40          // ceil(Nn/256)

static __device__ __forceinline__ float lrelu(float x) { return fmaxf(x, SLOPE * x); }

// ---------------- CSR build ----------------
__global__ void init_counts(int* counts) {
    int i = blockIdx.x * 256 + threadIdx.x;
    if (i < Nn) counts[i] = 1;  // self loop
}

__global__ void count_edges(const int* __restrict__ ei, int* counts) {
    int e = blockIdx.x * 256 + threadIdx.x;
    if (e < Ee) atomicAdd(&counts[ei[Ee + e]], 1);
}

// two-level scan: block reduce -> 1-wave scan -> block scan + base
__global__ __launch_bounds__(256) void reduce_counts(const int* __restrict__ counts,
                                                     int* __restrict__ blocksums) {
    __shared__ int sd[256];
    int t = threadIdx.x, i = blockIdx.x * 256 + t;
    sd[t] = (i < Nn) ? counts[i] : 0;
    __syncthreads();
    for (int off = 128; off > 0; off >>= 1) {
        if (t < off) sd[t] += sd[t + off];
        __syncthreads();
    }
    if (t == 0) blocksums[blockIdx.x] = sd[0];
}

__global__ __launch_bounds__(64) void scan_sums(int* blocksums) {
    int t = threadIdx.x;
    int orig = (t < NB) ? blocksums[t] : 0;
    int v = orig;
    for (int off = 1; off < 64; off <<= 1) {
        int u = __shfl_up(v, off);
        if (t >= off) v += u;
    }
    if (t < NB) blocksums[t] = v - orig;  // exclusive
}

__global__ __launch_bounds__(256) void scan_final(const int* __restrict__ counts,
                                                  const int* __restrict__ blocksums,
                                                  int* __restrict__ offsets,
                                                  int* __restrict__ cursor) {
    __shared__ int sd[256];
    int t = threadIdx.x, i = blockIdx.x * 256 + t;
    int v = (i < Nn) ? counts[i] : 0;
    sd[t] = v;
    __syncthreads();
    int x = v;
    for (int off = 1; off < 256; off <<= 1) {
        int u = (t >= off) ? sd[t - off] : 0;
        __syncthreads();
        x += u;
        sd[t] = x;
        __syncthreads();
    }
    int base = blocksums[blockIdx.x];
    int e = base + x - v;  // exclusive
    if (i < Nn) {
        offsets[i] = e;
        cursor[i] = e;
        if (i == Nn - 1) offsets[Nn] = e + v;
    }
}

__global__ void scatter_edges(const int* __restrict__ ei, int* cursor, int* __restrict__ csr) {
    int t = blockIdx.x * 256 + threadIdx.x;
    if (t >= EE) return;
    int src, dst;
    if (t < Ee) { src = ei[t]; dst = ei[Ee + t]; }
    else        { src = t - Ee; dst = t - Ee; }
    int pos = atomicAdd(&cursor[dst], 1);
    csr[pos] = src;
}

// ---------------- fp32 tiled GEMM (64x64x16, 4x4 per thread, padded LDS) ----------------
__global__ __launch_bounds__(256) void gemm64(const float* __restrict__ A,
                                              const float* __restrict__ B,
                                              float* __restrict__ C,
                                              int M, int N, int K) {
    __shared__ float As[16][72];
    __shared__ float Bs[16][72];
    const int tid = threadIdx.x;
    const int bm = blockIdx.x * 64, bn = blockIdx.y * 64;
    const int tx = tid & 15, ty = tid >> 4;
    const int arow = tid >> 2, acol = (tid & 3) << 2;
    const int brow = tid >> 4, bcol = (tid & 15) << 2;
    float acc[4][4] = {};
    for (int k0 = 0; k0 < K; k0 += 16) {
        float4 av;
        int gm = bm + arow;
        if (gm < M) av = *(const float4*)(A + (size_t)gm * K + k0 + acol);
        else av = make_float4(0.f, 0.f, 0.f, 0.f);
        As[acol + 0][arow] = av.x;
        As[acol + 1][arow] = av.y;
        As[acol + 2][arow] = av.z;
        As[acol + 3][arow] = av.w;
        *(float4*)&Bs[brow][bcol] = *(const float4*)(B + (size_t)(k0 + brow) * N + bn + bcol);
        __syncthreads();
#pragma unroll
        for (int k = 0; k < 16; k++) {
            float4 a = *(const float4*)&As[k][ty << 2];
            float4 b = *(const float4*)&Bs[k][tx << 2];
            float ar[4] = {a.x, a.y, a.z, a.w};
            float br[4] = {b.x, b.y, b.z, b.w};
#pragma unroll
            for (int i = 0; i < 4; i++)
#pragma unroll
                for (int j = 0; j < 4; j++) acc[i][j] += ar[i] * br[j];
        }
        __syncthreads();
    }
#pragma unroll
    for (int i = 0; i < 4; i++) {
        int gm = bm + (ty << 2) + i;
        if (gm < M) {
            float4 o = make_float4(acc[i][0], acc[i][1], acc[i][2], acc[i][3]);
            *(float4*)(C + (size_t)gm * N + bn + (tx << 2)) = o;
        }
    }
}

// ---------------- alpha_s / alpha_d per (node, head) ----------------
__global__ __launch_bounds__(256) void alphas_kernel(const float* __restrict__ h,
                                                     const float* __restrict__ a_src,
                                                     const float* __restrict__ a_dst,
                                                     float* __restrict__ as_out,
                                                     float* __restrict__ ad_out) {
    int n = blockIdx.x;
    int head = threadIdx.x >> 6;
    int lane = threadIdx.x & 63;
    const float* hp = h + (size_t)n * F1 + head * 128 + lane * 2;
    const float* sp = a_src + head * 128 + lane * 2;
    const float* dp = a_dst + head * 128 + lane * 2;
    float2 hv = *(const float2*)hp;
    float2 sv = *(const float2*)sp;
    float2 dv = *(const float2*)dp;
    float s = hv.x * sv.x + hv.y * sv.y;
    float d = hv.x * dv.x + hv.y * dv.y;
    for (int off = 32; off > 0; off >>= 1) {
        s += __shfl_xor(s, off);
        d += __shfl_xor(d, off);
    }
    if (lane == 0) {
        as_out[n * NH + head] = s;
        ad_out[n * NH + head] = d;
    }
}

// ---------------- softmax pass A ----------------
__global__ __launch_bounds__(256) void passA(const int* __restrict__ offsets,
                                             const int* __restrict__ csr,
                                             const float* __restrict__ as,
                                             const float* __restrict__ ad,
                                             float* __restrict__ wedge,
                                             float* __restrict__ invd) {
    int n = blockIdx.x * 4 + (threadIdx.x >> 6);
    int lane = threadIdx.x & 63;
    int start = offsets[n], end = offsets[n + 1];
    float4 adv = *(const float4*)&ad[n * NH];
    float m0 = -1e30f, m1 = -1e30f, m2 = -1e30f, m3 = -1e30f;
    for (int idx = start + lane; idx < end; idx += 64) {
        int src = csr[idx];
        float4 asv = *(const float4*)&as[src * NH];
        m0 = fmaxf(m0, lrelu(asv.x + adv.x));
        m1 = fmaxf(m1, lrelu(asv.y + adv.y));
        m2 = fmaxf(m2, lrelu(asv.z + adv.z));
        m3 = fmaxf(m3, lrelu(asv.w + adv.w));
    }
    for (int off = 32; off > 0; off >>= 1) {
        m0 = fmaxf(m0, __shfl_xor(m0, off));
        m1 = fmaxf(m1, __shfl_xor(m1, off));
        m2 = fmaxf(m2, __shfl_xor(m2, off));
        m3 = fmaxf(m3, __shfl_xor(m3, off));
    }
    float s0 = 0.f, s1 = 0.f, s2 = 0.f, s3 = 0.f;
    for (int idx = start + lane; idx < end; idx += 64) {
        int src = csr[idx];
        float4 asv = *(const float4*)&as[src * NH];
        float e0 = __expf(lrelu(asv.x + adv.x) - m0);
        float e1 = __expf(lrelu(asv.y + adv.y) - m1);
        float e2 = __expf(lrelu(asv.z + adv.z) - m2);
        float e3 = __expf(lrelu(asv.w + adv.w) - m3);
        *(float4*)&wedge[(size_t)idx * NH] = make_float4(e0, e1, e2, e3);
        s0 += e0; s1 += e1; s2 += e2; s3 += e3;
    }
    for (int off = 32; off > 0; off >>= 1) {
        s0 += __shfl_xor(s0, off);
        s1 += __shfl_xor(s1, off);
        s2 += __shfl_xor(s2, off);
        s3 += __shfl_xor(s3, off);
    }
    if (lane == 0) {
        *(float4*)&invd[n * NH] = make_float4(1.f / (s0 + 1e-16f), 1.f / (s1 + 1e-16f),
                                              1.f / (s2 + 1e-16f), 1.f / (s3 + 1e-16f));
    }
}

// ---------------- pass B layer 1: 128 thr, float4/thr, 4-edge unroll ----------------
__global__ __launch_bounds__(128) void passB1(const int* __restrict__ offsets,
                                              const int* __restrict__ csr,
                                              const float* __restrict__ wedge,
                                              const float* __restrict__ invd,
                                              const float* __restrict__ h1,
                                              const float* __restrict__ b1,
                                              float* __restrict__ agg) {
    int n = blockIdx.x;
    int t = threadIdx.x;
    int c = t << 2;
    int head = t >> 5;
    int start = offsets[n], end = offsets[n + 1];
    float inv = invd[n * NH + head];
    float ax = 0.f, ay = 0.f, az = 0.f, aw = 0.f;
    int idx = start;
    for (; idx + 3 < end; idx += 4) {
        int s0 = csr[idx], s1 = csr[idx + 1], s2 = csr[idx + 2], s3 = csr[idx + 3];
        float w0 = wedge[(size_t)idx * NH + head];
        float w1 = wedge[(size_t)(idx + 1) * NH + head];
        float w2 = wedge[(size_t)(idx + 2) * NH + head];
        float w3 = wedge[(size_t)(idx + 3) * NH + head];
        float4 v0 = *(const float4*)&h1[(size_t)s0 * F1 + c];
        float4 v1 = *(const float4*)&h1[(size_t)s1 * F1 + c];
        float4 v2 = *(const float4*)&h1[(size_t)s2 * F1 + c];
        float4 v3 = *(const float4*)&h1[(size_t)s3 * F1 + c];
        ax += v0.x * w0 + v1.x * w1 + v2.x * w2 + v3.x * w3;
        ay += v0.y * w0 + v1.y * w1 + v2.y * w2 + v3.y * w3;
        az += v0.z * w0 + v1.z * w1 + v2.z * w2 + v3.z * w3;
        aw += v0.w * w0 + v1.w * w1 + v2.w * w2 + v3.w * w3;
    }
    for (; idx < end; ++idx) {
        int s0 = csr[idx];
        float w0 = wedge[(size_t)idx * NH + head];
        float4 v0 = *(const float4*)&h1[(size_t)s0 * F1 + c];
        ax += v0.x * w0; ay += v0.y * w0; az += v0.z * w0; aw += v0.w * w0;
    }
    float4 bv = *(const float4*)&b1[c];
    float4 o;
    o.x = fmaxf(ax * inv + bv.x, 0.f);
    o.y = fmaxf(ay * inv + bv.y, 0.f);
    o.z = fmaxf(az * inv + bv.z, 0.f);
    o.w = fmaxf(aw * inv + bv.w, 0.f);
    *(float4*)&agg[(size_t)n * F1 + c] = o;
}

// ---------------- pass B layer 2: float4/thr + LDS head-mean epilogue ----------------
__global__ __launch_bounds__(128) void passB2(const int* __restrict__ offsets,
                                              const int* __restrict__ csr,
                                              const float* __restrict__ wedge,
                                              const float* __restrict__ invd,
                                              const float* __restrict__ h2,
                                              const float* __restrict__ b2,
                                              float* __restrict__ out) {
    __shared__ float4 red[128];
    int n = blockIdx.x;
    int t = threadIdx.x;
    int c = t << 2;
    int head = t >> 5;
    int start = offsets[n], end = offsets[n + 1];
    float inv = invd[n * NH + head];
    float ax = 0.f, ay = 0.f, az = 0.f, aw = 0.f;
    int idx = start;
    for (; idx + 3 < end; idx += 4) {
        int s0 = csr[idx], s1 = csr[idx + 1], s2 = csr[idx + 2], s3 = csr[idx + 3];
        float w0 = wedge[(size_t)idx * NH + head];
        float w1 = wedge[(size_t)(idx + 1) * NH + head];
        float w2 = wedge[(size_t)(idx + 2) * NH + head];
        float w3 = wedge[(size_t)(idx + 3) * NH + head];
        float4 v0 = *(const float4*)&h2[(size_t)s0 * F2 + c];
        float4 v1 = *(const float4*)&h2[(size_t)s1 * F2 + c];
        float4 v2 = *(const float4*)&h2[(size_t)s2 * F2 + c];
        float4 v3 = *(const float4*)&h2[(size_t)s3 * F2 + c];
        ax += v0.x * w0 + v1.x * w1 + v2.x * w2 + v3.x * w3;
        ay += v0.y * w0 + v1.y * w1 + v2.y * w2 + v3.y * w3;
        az += v0.z * w0 + v1.z * w1 + v2.z * w2 + v3.z * w3;
        aw += v0.w * w0 + v1.w * w1 + v2.w * w2 + v3.w * w3;
    }
    for (; idx < end; ++idx) {
        int s0 = csr[idx];
        float w0 = wedge[(size_t)idx * NH + head];
        float4 v0 = *(const float4*)&h2[(size_t)s0 * F2 + c];
        ax += v0.x * w0; ay += v0.y * w0; az += v0.z * w0; aw += v0.w * w0;
    }
    red[t] = make_float4(ax * inv, ay * inv, az * inv, aw * inv);
    __syncthreads();
    if (t < 32) {
        float4 r0 = red[t], r1 = red[t + 32], r2 = red[t + 64], r3 = red[t + 96];
        float4 bv = *(const float4*)&b2[t << 2];
        float4 o;
        o.x = 0.25f * (r0.x + r1.x + r2.x + r3.x) + bv.x;
        o.y = 0.25f * (r0.y + r1.y + r2.y + r3.y) + bv.y;
        o.z = 0.25f * (r0.z + r1.z + r2.z + r3.z) + bv.z;
        o.w = 0.25f * (r0.w + r1.w + r2.w + r3.w) + bv.w;
        *(float4*)&out[(size_t)n * OUTC + (t << 2)] = o;
    }
}

extern "C" void kernel_launch(void* const* d_in, const int* in_sizes, int n_in,
                              void* d_out, int out_size, void* d_ws, size_t ws_size,
                              hipStream_t stream) {
    const float* x      = (const float*)d_in[0];
    const int*   ei     = (const int*)d_in[1];
    const float* W1     = (const float*)d_in[2];
    const float* a_src1 = (const float*)d_in[3];
    const float* a_dst1 = (const float*)d_in[4];
    const float* b1     = (const float*)d_in[5];
    const float* W2     = (const float*)d_in[6];
    const float* a_src2 = (const float*)d_in[7];
    const float* a_dst2 = (const float*)d_in[8];
    const float* b2     = (const float*)d_in[9];
    float* out = (float*)d_out;

    const size_t NF = (size_t)Nn * F1;
    float* f = (float*)d_ws;
    float* h1    = f;
    float* h2    = h1 + NF;
    float* agg1  = h2 + NF;
    float* as1   = agg1 + NF;
    float* ad1   = as1 + Nn * NH;
    float* as2   = ad1 + Nn * NH;
    float* ad2   = as2 + Nn * NH;
    float* invd1 = ad2 + Nn * NH;
    float* invd2 = invd1 + Nn * NH;
    float* wedge = invd2 + Nn * NH;     // EE*NH floats
    int* counts    = (int*)(wedge + (size_t)EE * NH);
    int* offsets   = counts + Nn;
    int* cursor    = offsets + Nn + 1;
    int* csr       = cursor + Nn;
    int* blocksums = csr + EE;

    // CSR build
    init_counts<<<(Nn + 255) / 256, 256, 0, stream>>>(counts);
    count_edges<<<(Ee + 255) / 256, 256, 0, stream>>>(ei, counts);
    reduce_counts<<<NB, 256, 0, stream>>>(counts, blocksums);
    scan_sums<<<1, 64, 0, stream>>>(blocksums);
    scan_final<<<NB, 256, 0, stream>>>(counts, blocksums, offsets, cursor);
    scatter_edges<<<(EE + 255) / 256, 256, 0, stream>>>(ei, cursor, csr);

    // Layer 1
    gemm64<<<dim3((Nn + 63) / 64, F1 / 64), 256, 0, stream>>>(x, W1, h1, Nn, F1, INF_);
    alphas_kernel<<<Nn, 256, 0, stream>>>(h1, a_src1, a_dst1, as1, ad1);
    passA<<<Nn / 4, 256, 0, stream>>>(offsets, csr, as1, ad1, wedge, invd1);
    passB1<<<Nn, 128, 0, stream>>>(offsets, csr, wedge, invd1, h1, b1, agg1);

    // Layer 2
    gemm64<<<dim3((Nn + 63) / 64, F2 / 64), 256, 0, stream>>>(agg1, W2, h2, Nn, F2, F1);
    alphas_kernel<<<Nn, 256, 0, stream>>>(h2, a_src2, a_dst2, as2, ad2);
    passA<<<Nn / 4, 256, 0, stream>>>(offsets, csr, as2, ad2, wedge, invd2);
    passB2<<<Nn, 128, 0, stream>>>(offsets, csr, wedge, invd2, h2, b2, out);
}